// Round 16
// baseline (167.660 us; speedup 1.0000x reference)
//
#include <hip/hip_runtime.h>
#include <hip/hip_bf16.h>

#define N_NODES 50000
#define N_EDGES 600000
#define HIDDEN 128
#define BCAP 64   // bucket capacity per node; Poisson(12) tail @64 ~ 1e-30

typedef __attribute__((ext_vector_type(8))) short bf16x8;
typedef __attribute__((ext_vector_type(4))) float f32x4;

// f32 -> bf16 round-to-nearest-even
__device__ __forceinline__ short f2bf(float f) {
    unsigned u = __builtin_bit_cast(unsigned, f);
    u += 0x7fff + ((u >> 16) & 1);
    return (short)(u >> 16);
}
__device__ __forceinline__ float bf2f(unsigned short s) {
    unsigned u = ((unsigned)s) << 16;
    return __builtin_bit_cast(float, u);
}

// ---------------------------------------------------------------------------
// QKV projection via bf16 MFMA; M-tile = 128 nodes, 512 threads (8 waves).
// W fragments converted per block, inline, from f32 Wq/Wk/Wv (24 KB L2-hot
// per block; same addressing the former wprep kernel used) -- removes one
// dispatch + graph gap. cnt zeroing piggybacked.
// ---------------------------------------------------------------------------
__global__ __launch_bounds__(512, 2) void qkv_mfma_kernel(
    const float* __restrict__ x,
    const float* __restrict__ Wq, const float* __restrict__ Wk,
    const float* __restrict__ Wv,
    unsigned short* __restrict__ q, unsigned short* __restrict__ k,
    unsigned short* __restrict__ v,
    int* __restrict__ cnt, int n_nodes)
{
    __shared__ bf16x8 xs[2048];  // 128 rows x 16 chunks (16 B each), swizzled

    const int tid   = threadIdx.x;
    const int node0 = blockIdx.x * 128;

    // Piggyback: zero the per-node counters.
    {
        int i = blockIdx.x * 512 + tid;
        if (i < n_nodes) cnt[i] = 0;
    }

    for (int i = 0; i < 4; ++i) {
        int idx = tid + i * 512;
        int row = idx >> 4;
        int ch  = idx & 15;
        int node = node0 + row;
        bf16x8 c = {0, 0, 0, 0, 0, 0, 0, 0};
        if (node < n_nodes) {
            const float* xp = x + (size_t)node * 128 + ch * 8;
            float4 f0 = *reinterpret_cast<const float4*>(xp);
            float4 f1 = *reinterpret_cast<const float4*>(xp + 4);
            c[0] = f2bf(f0.x); c[1] = f2bf(f0.y); c[2] = f2bf(f0.z); c[3] = f2bf(f0.w);
            c[4] = f2bf(f1.x); c[5] = f2bf(f1.y); c[6] = f2bf(f1.z); c[7] = f2bf(f1.w);
        }
        xs[row * 16 + (ch ^ (row & 7))] = c;
    }

    const int wave = tid >> 6;
    const int lane = tid & 63;
    const int ln16 = lane & 15;
    const int kg   = lane >> 4;

    // Inline W -> bf16 fragment conversion (formerly wprep).
    bf16x8 wfrag[3][4];
    const int ctbase = wave * 3;
#pragma unroll
    for (int t = 0; t < 3; ++t) {
        int ct = ctbase + t;
        const float* Wm = (ct < 8) ? Wq : (ct < 16 ? Wk : Wv);
        int colbase = (ct & 7) * 16;
        const float* wrow = Wm + (size_t)(colbase + ln16) * 128;
#pragma unroll
        for (int s = 0; s < 4; ++s) {
            const float* wp = wrow + s * 32 + kg * 8;
            float4 f0 = *reinterpret_cast<const float4*>(wp);
            float4 f1 = *reinterpret_cast<const float4*>(wp + 4);
            bf16x8 c;
            c[0] = f2bf(f0.x); c[1] = f2bf(f0.y); c[2] = f2bf(f0.z); c[3] = f2bf(f0.w);
            c[4] = f2bf(f1.x); c[5] = f2bf(f1.y); c[6] = f2bf(f1.z); c[7] = f2bf(f1.w);
            wfrag[t][s] = c;
        }
    }

    __syncthreads();

    for (int rg = 0; rg < 8; ++rg) {
        bf16x8 afrag[4];
        int row = rg * 16 + ln16;
#pragma unroll
        for (int s = 0; s < 4; ++s) {
            int ch = s * 4 + kg;
            afrag[s] = xs[row * 16 + (ch ^ (row & 7))];
        }
#pragma unroll
        for (int t = 0; t < 3; ++t) {
            f32x4 acc = {0.f, 0.f, 0.f, 0.f};
#pragma unroll
            for (int s = 0; s < 4; ++s)
                acc = __builtin_amdgcn_mfma_f32_16x16x32_bf16(afrag[s], wfrag[t][s], acc, 0, 0, 0);
            int ct = ctbase + t;
            unsigned short* outp = (ct < 8) ? q : (ct < 16 ? k : v);
            int colbase = (ct & 7) * 16;
            int rbase = node0 + rg * 16 + kg * 4;
#pragma unroll
            for (int i2 = 0; i2 < 4; ++i2) {
                int node = rbase + i2;
                if (node < n_nodes)
                    outp[(size_t)node * 128 + colbase + ln16] =
                        (unsigned short)f2bf(acc[i2]);
            }
        }
    }
}

// ---------------------------------------------------------------------------
// Fused edge pass: 8 lanes per edge, one head per lane (no cross-lane
// reduce); slot broadcast via ds_bpermute. Plain float4 w_ij loads.
// (round-11 version, measured best)
// ---------------------------------------------------------------------------
__global__ __launch_bounds__(256) void edge_kernel(
    const unsigned short* __restrict__ q, const unsigned short* __restrict__ k,
    const float* __restrict__ w_ij, const int* __restrict__ edge_index,
    const float* __restrict__ cutoff, int* __restrict__ cnt,
    int* __restrict__ bsrc, unsigned short* __restrict__ balpha, int n_edges)
{
    const int l8 = threadIdx.x & 7;          // head index
    const int e = blockIdx.x * 32 + (threadIdx.x >> 3);
    if (e >= n_edges) return;

    const int src = edge_index[e];
    const int dst = edge_index[n_edges + e];
    const float c = cutoff[e];

    const float* wp = w_ij + (size_t)e * 128 + l8 * 16;
    const float4 w0 = *reinterpret_cast<const float4*>(wp);
    const float4 w1 = *reinterpret_cast<const float4*>(wp + 4);
    const float4 w2 = *reinterpret_cast<const float4*>(wp + 8);
    const float4 w3 = *reinterpret_cast<const float4*>(wp + 12);
    const bf16x8 q0 = *reinterpret_cast<const bf16x8*>(q + (size_t)dst * 128 + l8 * 16);
    const bf16x8 q1 = *reinterpret_cast<const bf16x8*>(q + (size_t)dst * 128 + l8 * 16 + 8);
    const bf16x8 k0 = *reinterpret_cast<const bf16x8*>(k + (size_t)src * 128 + l8 * 16);
    const bf16x8 k1 = *reinterpret_cast<const bf16x8*>(k + (size_t)src * 128 + l8 * 16 + 8);

    float s = bf2f((unsigned short)q0[0]) * w0.x * bf2f((unsigned short)k0[0])
            + bf2f((unsigned short)q0[1]) * w0.y * bf2f((unsigned short)k0[1])
            + bf2f((unsigned short)q0[2]) * w0.z * bf2f((unsigned short)k0[2])
            + bf2f((unsigned short)q0[3]) * w0.w * bf2f((unsigned short)k0[3])
            + bf2f((unsigned short)q0[4]) * w1.x * bf2f((unsigned short)k0[4])
            + bf2f((unsigned short)q0[5]) * w1.y * bf2f((unsigned short)k0[5])
            + bf2f((unsigned short)q0[6]) * w1.z * bf2f((unsigned short)k0[6])
            + bf2f((unsigned short)q0[7]) * w1.w * bf2f((unsigned short)k0[7])
            + bf2f((unsigned short)q1[0]) * w2.x * bf2f((unsigned short)k1[0])
            + bf2f((unsigned short)q1[1]) * w2.y * bf2f((unsigned short)k1[1])
            + bf2f((unsigned short)q1[2]) * w2.z * bf2f((unsigned short)k1[2])
            + bf2f((unsigned short)q1[3]) * w2.w * bf2f((unsigned short)k1[3])
            + bf2f((unsigned short)q1[4]) * w3.x * bf2f((unsigned short)k1[4])
            + bf2f((unsigned short)q1[5]) * w3.y * bf2f((unsigned short)k1[5])
            + bf2f((unsigned short)q1[6]) * w3.z * bf2f((unsigned short)k1[6])
            + bf2f((unsigned short)q1[7]) * w3.w * bf2f((unsigned short)k1[7]);

    int slot = 0;
    if (l8 == 0) slot = atomicAdd(&cnt[dst], 1);
    // broadcast lane (group base) -> all 8 lanes of this edge's group
    {
        int gbase = (threadIdx.x & 63) & ~7;
        slot = __builtin_amdgcn_ds_bpermute(gbase << 2, slot);
    }

    if (slot < BCAP) {
        const size_t b = (size_t)dst * BCAP + slot;
        if (l8 == 0) bsrc[b] = src;
        balpha[b * 8 + l8] = (unsigned short)f2bf(s * 0.25f * c);  // 1/sqrt(16)
    }
}

// ---------------------------------------------------------------------------
// Node-parallel gather: one node per WAVE, 8 ways x 8 lanes, depth-2
// rotating prefetch, direct per-slot bsrc reads. (round-15 version)
// ---------------------------------------------------------------------------
__global__ __launch_bounds__(256) void gather_kernel(
    const unsigned short* __restrict__ v, const int* __restrict__ cnt,
    const int* __restrict__ bsrc, const unsigned short* __restrict__ balpha,
    float* __restrict__ out, int n_nodes)
{
    const int lane = threadIdx.x & 63;
    const int l8   = lane & 7;    // head index; elems [l8*16, l8*16+16)
    const int way  = lane >> 3;   // 0..7
    const int node = blockIdx.x * 4 + (threadIdx.x >> 6);
    if (node >= n_nodes) return;

    const int n = min(cnt[node], BCAP);
    const size_t base = (size_t)node * BCAP;

    float acc[16];
#pragma unroll
    for (int j = 0; j < 16; ++j) acc[j] = 0.f;

    int s = way;
    float aA = 0.f, aB = 0.f;
    bf16x8 vA0 = {0, 0, 0, 0, 0, 0, 0, 0};
    bf16x8 vA1 = {0, 0, 0, 0, 0, 0, 0, 0};
    bf16x8 vB0 = {0, 0, 0, 0, 0, 0, 0, 0};
    bf16x8 vB1 = {0, 0, 0, 0, 0, 0, 0, 0};
    if (s < n) {
        int sr = bsrc[base + s];
        aA = bf2f(balpha[(base + s) * 8 + l8]);
        const unsigned short* vp = v + (size_t)sr * 128 + l8 * 16;
        vA0 = *reinterpret_cast<const bf16x8*>(vp);
        vA1 = *reinterpret_cast<const bf16x8*>(vp + 8);
    }
    if (s + 8 < n) {
        int sr = bsrc[base + s + 8];
        aB = bf2f(balpha[(base + s + 8) * 8 + l8]);
        const unsigned short* vp = v + (size_t)sr * 128 + l8 * 16;
        vB0 = *reinterpret_cast<const bf16x8*>(vp);
        vB1 = *reinterpret_cast<const bf16x8*>(vp + 8);
    }

    for (; s < n; s += 8) {
        float aC = 0.f;
        bf16x8 vC0 = {0, 0, 0, 0, 0, 0, 0, 0};
        bf16x8 vC1 = {0, 0, 0, 0, 0, 0, 0, 0};
        if (s + 16 < n) {
            int sr = bsrc[base + s + 16];
            aC = bf2f(balpha[(base + s + 16) * 8 + l8]);
            const unsigned short* vp = v + (size_t)sr * 128 + l8 * 16;
            vC0 = *reinterpret_cast<const bf16x8*>(vp);
            vC1 = *reinterpret_cast<const bf16x8*>(vp + 8);
        }
#pragma unroll
        for (int j = 0; j < 8; ++j)
            acc[j] += aA * bf2f((unsigned short)vA0[j]);
#pragma unroll
        for (int j = 0; j < 8; ++j)
            acc[8 + j] += aA * bf2f((unsigned short)vA1[j]);
        aA = aB; vA0 = vB0; vA1 = vB1;
        aB = aC; vB0 = vC0; vB1 = vC1;
    }

    // combine the eight ways
#pragma unroll
    for (int j = 0; j < 16; ++j) {
        acc[j] += __shfl_xor(acc[j], 8);
        acc[j] += __shfl_xor(acc[j], 16);
        acc[j] += __shfl_xor(acc[j], 32);
    }

    if (way == 0) {
        float* op = out + (size_t)node * 128 + l8 * 16;
        *reinterpret_cast<float4*>(op)      = make_float4(acc[0],  acc[1],  acc[2],  acc[3]);
        *reinterpret_cast<float4*>(op + 4)  = make_float4(acc[4],  acc[5],  acc[6],  acc[7]);
        *reinterpret_cast<float4*>(op + 8)  = make_float4(acc[8],  acc[9],  acc[10], acc[11]);
        *reinterpret_cast<float4*>(op + 12) = make_float4(acc[12], acc[13], acc[14], acc[15]);
    }
}

extern "C" void kernel_launch(void* const* d_in, const int* in_sizes, int n_in,
                              void* d_out, int out_size, void* d_ws, size_t ws_size,
                              hipStream_t stream) {
    const float* x    = (const float*)d_in[0];
    const float* w_ij = (const float*)d_in[1];
    const int* eidx   = (const int*)d_in[2];
    const float* cut  = (const float*)d_in[3];
    const float* Wq   = (const float*)d_in[4];
    const float* Wk   = (const float*)d_in[5];
    const float* Wv   = (const float*)d_in[6];
    float* out = (float*)d_out;

    const size_t nq = (size_t)N_NODES * HIDDEN;
    unsigned short* q = (unsigned short*)d_ws;
    unsigned short* k = q + nq;
    unsigned short* v = k + nq;
    int* cnt = (int*)(v + nq);
    int* bsrc = cnt + N_NODES;
    unsigned short* balpha = (unsigned short*)(bsrc + (size_t)N_NODES * BCAP);

    // QKV projection (MFMA, bf16 out, M=128, inline W conversion);
    // also zeroes cnt[].
    dim3 ggrid((N_NODES + 127) / 128);
    qkv_mfma_kernel<<<ggrid, 512, 0, stream>>>(x, Wq, Wk, Wv, q, k, v, cnt, N_NODES);

    // Fused edge pass: alpha + slot-ordered bucket store (8 lanes/edge).
    dim3 egrid((N_EDGES + 31) / 32);
    edge_kernel<<<egrid, 256, 0, stream>>>(q, k, w_ij, eidx, cut, cnt,
                                           bsrc, balpha, N_EDGES);

    // Node-parallel gather (one node per wave, 8-way x 8-lane).
    dim3 ngrid((N_NODES + 3) / 4);
    gather_kernel<<<ngrid, 256, 0, stream>>>(v, cnt, bsrc, balpha, out, N_NODES);
}

// Round 17
// 163.769 us; speedup vs baseline: 1.0238x; 1.0238x over previous
//
#include <hip/hip_runtime.h>
#include <hip/hip_bf16.h>

#define N_NODES 50000
#define N_EDGES 600000
#define HIDDEN 128
#define BCAP 64   // bucket capacity per node; Poisson(12) tail @64 ~ 1e-30

typedef __attribute__((ext_vector_type(8))) short bf16x8;
typedef __attribute__((ext_vector_type(4))) float f32x4;

// f32 -> bf16 round-to-nearest-even
__device__ __forceinline__ short f2bf(float f) {
    unsigned u = __builtin_bit_cast(unsigned, f);
    u += 0x7fff + ((u >> 16) & 1);
    return (short)(u >> 16);
}
__device__ __forceinline__ float bf2f(unsigned short s) {
    unsigned u = ((unsigned)s) << 16;
    return __builtin_bit_cast(float, u);
}

// ---------------------------------------------------------------------------
// W pre-conversion: f32 Wq/Wk/Wv -> bf16 B-fragments in MFMA order.
// (separate kernel measured better than inline per-block conversion, r16)
// ---------------------------------------------------------------------------
__global__ __launch_bounds__(256) void wprep_kernel(
    const float* __restrict__ Wq, const float* __restrict__ Wk,
    const float* __restrict__ Wv, bf16x8* __restrict__ wb)
{
    int t = blockIdx.x * 256 + threadIdx.x;
    if (t >= 24 * 4 * 64) return;
    int ct   = t >> 8;
    int rem  = t & 255;
    int s    = rem >> 6;
    int lane = rem & 63;
    const float* Wm = (ct < 8) ? Wq : (ct < 16 ? Wk : Wv);
    int col = (ct & 7) * 16 + (lane & 15);
    int kb  = s * 32 + (lane >> 4) * 8;
    const float* wp = Wm + (size_t)col * 128 + kb;
    float4 f0 = *reinterpret_cast<const float4*>(wp);
    float4 f1 = *reinterpret_cast<const float4*>(wp + 4);
    bf16x8 c;
    c[0] = f2bf(f0.x); c[1] = f2bf(f0.y); c[2] = f2bf(f0.z); c[3] = f2bf(f0.w);
    c[4] = f2bf(f1.x); c[5] = f2bf(f1.y); c[6] = f2bf(f1.z); c[7] = f2bf(f1.w);
    wb[t] = c;
}

// ---------------------------------------------------------------------------
// QKV projection via bf16 MFMA; M-tile = 128 nodes, 512 threads (8 waves).
// D = x_frag(A) * W_frag(B); cnt zeroing piggybacked.
// ---------------------------------------------------------------------------
__global__ __launch_bounds__(512, 2) void qkv_mfma_kernel(
    const float* __restrict__ x, const bf16x8* __restrict__ wb,
    unsigned short* __restrict__ q, unsigned short* __restrict__ k,
    unsigned short* __restrict__ v,
    int* __restrict__ cnt, int n_nodes)
{
    __shared__ bf16x8 xs[2048];  // 128 rows x 16 chunks (16 B each), swizzled

    const int tid   = threadIdx.x;
    const int node0 = blockIdx.x * 128;

    // Piggyback: zero the per-node counters.
    {
        int i = blockIdx.x * 512 + tid;
        if (i < n_nodes) cnt[i] = 0;
    }

    for (int i = 0; i < 4; ++i) {
        int idx = tid + i * 512;
        int row = idx >> 4;
        int ch  = idx & 15;
        int node = node0 + row;
        bf16x8 c = {0, 0, 0, 0, 0, 0, 0, 0};
        if (node < n_nodes) {
            const float* xp = x + (size_t)node * 128 + ch * 8;
            float4 f0 = *reinterpret_cast<const float4*>(xp);
            float4 f1 = *reinterpret_cast<const float4*>(xp + 4);
            c[0] = f2bf(f0.x); c[1] = f2bf(f0.y); c[2] = f2bf(f0.z); c[3] = f2bf(f0.w);
            c[4] = f2bf(f1.x); c[5] = f2bf(f1.y); c[6] = f2bf(f1.z); c[7] = f2bf(f1.w);
        }
        xs[row * 16 + (ch ^ (row & 7))] = c;
    }

    const int wave = tid >> 6;
    const int lane = tid & 63;
    const int ln16 = lane & 15;
    const int kg   = lane >> 4;

    bf16x8 wfrag[3][4];
    const int ctbase = wave * 3;
#pragma unroll
    for (int t = 0; t < 3; ++t)
#pragma unroll
        for (int s = 0; s < 4; ++s)
            wfrag[t][s] = wb[(size_t)((ctbase + t) * 4 + s) * 64 + lane];

    __syncthreads();

    for (int rg = 0; rg < 8; ++rg) {
        bf16x8 afrag[4];
        int row = rg * 16 + ln16;
#pragma unroll
        for (int s = 0; s < 4; ++s) {
            int ch = s * 4 + kg;
            afrag[s] = xs[row * 16 + (ch ^ (row & 7))];
        }
#pragma unroll
        for (int t = 0; t < 3; ++t) {
            f32x4 acc = {0.f, 0.f, 0.f, 0.f};
#pragma unroll
            for (int s = 0; s < 4; ++s)
                acc = __builtin_amdgcn_mfma_f32_16x16x32_bf16(afrag[s], wfrag[t][s], acc, 0, 0, 0);
            int ct = ctbase + t;
            unsigned short* outp = (ct < 8) ? q : (ct < 16 ? k : v);
            int colbase = (ct & 7) * 16;
            int rbase = node0 + rg * 16 + kg * 4;
#pragma unroll
            for (int i2 = 0; i2 < 4; ++i2) {
                int node = rbase + i2;
                if (node < n_nodes)
                    outp[(size_t)node * 128 + colbase + ln16] =
                        (unsigned short)f2bf(acc[i2]);
            }
        }
    }
}

// ---------------------------------------------------------------------------
// Fused edge pass: 8 lanes per edge, one head per lane (no cross-lane
// reduce); slot broadcast via ds_bpermute. Plain float4 w_ij loads
// (nt loads regress the stream by ~14 us -- round-12 lesson).
// ---------------------------------------------------------------------------
__global__ __launch_bounds__(256) void edge_kernel(
    const unsigned short* __restrict__ q, const unsigned short* __restrict__ k,
    const float* __restrict__ w_ij, const int* __restrict__ edge_index,
    const float* __restrict__ cutoff, int* __restrict__ cnt,
    int* __restrict__ bsrc, unsigned short* __restrict__ balpha, int n_edges)
{
    const int l8 = threadIdx.x & 7;          // head index
    const int e = blockIdx.x * 32 + (threadIdx.x >> 3);
    if (e >= n_edges) return;

    const int src = edge_index[e];
    const int dst = edge_index[n_edges + e];
    const float c = cutoff[e];

    const float* wp = w_ij + (size_t)e * 128 + l8 * 16;
    const float4 w0 = *reinterpret_cast<const float4*>(wp);
    const float4 w1 = *reinterpret_cast<const float4*>(wp + 4);
    const float4 w2 = *reinterpret_cast<const float4*>(wp + 8);
    const float4 w3 = *reinterpret_cast<const float4*>(wp + 12);
    const bf16x8 q0 = *reinterpret_cast<const bf16x8*>(q + (size_t)dst * 128 + l8 * 16);
    const bf16x8 q1 = *reinterpret_cast<const bf16x8*>(q + (size_t)dst * 128 + l8 * 16 + 8);
    const bf16x8 k0 = *reinterpret_cast<const bf16x8*>(k + (size_t)src * 128 + l8 * 16);
    const bf16x8 k1 = *reinterpret_cast<const bf16x8*>(k + (size_t)src * 128 + l8 * 16 + 8);

    float s = bf2f((unsigned short)q0[0]) * w0.x * bf2f((unsigned short)k0[0])
            + bf2f((unsigned short)q0[1]) * w0.y * bf2f((unsigned short)k0[1])
            + bf2f((unsigned short)q0[2]) * w0.z * bf2f((unsigned short)k0[2])
            + bf2f((unsigned short)q0[3]) * w0.w * bf2f((unsigned short)k0[3])
            + bf2f((unsigned short)q0[4]) * w1.x * bf2f((unsigned short)k0[4])
            + bf2f((unsigned short)q0[5]) * w1.y * bf2f((unsigned short)k0[5])
            + bf2f((unsigned short)q0[6]) * w1.z * bf2f((unsigned short)k0[6])
            + bf2f((unsigned short)q0[7]) * w1.w * bf2f((unsigned short)k0[7])
            + bf2f((unsigned short)q1[0]) * w2.x * bf2f((unsigned short)k1[0])
            + bf2f((unsigned short)q1[1]) * w2.y * bf2f((unsigned short)k1[1])
            + bf2f((unsigned short)q1[2]) * w2.z * bf2f((unsigned short)k1[2])
            + bf2f((unsigned short)q1[3]) * w2.w * bf2f((unsigned short)k1[3])
            + bf2f((unsigned short)q1[4]) * w3.x * bf2f((unsigned short)k1[4])
            + bf2f((unsigned short)q1[5]) * w3.y * bf2f((unsigned short)k1[5])
            + bf2f((unsigned short)q1[6]) * w3.z * bf2f((unsigned short)k1[6])
            + bf2f((unsigned short)q1[7]) * w3.w * bf2f((unsigned short)k1[7]);

    int slot = 0;
    if (l8 == 0) slot = atomicAdd(&cnt[dst], 1);
    // broadcast lane (group base) -> all 8 lanes of this edge's group
    {
        int gbase = (threadIdx.x & 63) & ~7;
        slot = __builtin_amdgcn_ds_bpermute(gbase << 2, slot);
    }

    if (slot < BCAP) {
        const size_t b = (size_t)dst * BCAP + slot;
        if (l8 == 0) bsrc[b] = src;
        balpha[b * 8 + l8] = (unsigned short)f2bf(s * 0.25f * c);  // 1/sqrt(16)
    }
}

// ---------------------------------------------------------------------------
// Node-parallel gather: one node per WAVE, 8 ways x 8 lanes, depth-2
// rotating prefetch, direct per-slot bsrc reads (no variable-lane shuffles
// -- round-10 lesson).
// ---------------------------------------------------------------------------
__global__ __launch_bounds__(256) void gather_kernel(
    const unsigned short* __restrict__ v, const int* __restrict__ cnt,
    const int* __restrict__ bsrc, const unsigned short* __restrict__ balpha,
    float* __restrict__ out, int n_nodes)
{
    const int lane = threadIdx.x & 63;
    const int l8   = lane & 7;    // head index; elems [l8*16, l8*16+16)
    const int way  = lane >> 3;   // 0..7
    const int node = blockIdx.x * 4 + (threadIdx.x >> 6);
    if (node >= n_nodes) return;

    const int n = min(cnt[node], BCAP);
    const size_t base = (size_t)node * BCAP;

    float acc[16];
#pragma unroll
    for (int j = 0; j < 16; ++j) acc[j] = 0.f;

    int s = way;
    float aA = 0.f, aB = 0.f;
    bf16x8 vA0 = {0, 0, 0, 0, 0, 0, 0, 0};
    bf16x8 vA1 = {0, 0, 0, 0, 0, 0, 0, 0};
    bf16x8 vB0 = {0, 0, 0, 0, 0, 0, 0, 0};
    bf16x8 vB1 = {0, 0, 0, 0, 0, 0, 0, 0};
    if (s < n) {
        int sr = bsrc[base + s];
        aA = bf2f(balpha[(base + s) * 8 + l8]);
        const unsigned short* vp = v + (size_t)sr * 128 + l8 * 16;
        vA0 = *reinterpret_cast<const bf16x8*>(vp);
        vA1 = *reinterpret_cast<const bf16x8*>(vp + 8);
    }
    if (s + 8 < n) {
        int sr = bsrc[base + s + 8];
        aB = bf2f(balpha[(base + s + 8) * 8 + l8]);
        const unsigned short* vp = v + (size_t)sr * 128 + l8 * 16;
        vB0 = *reinterpret_cast<const bf16x8*>(vp);
        vB1 = *reinterpret_cast<const bf16x8*>(vp + 8);
    }

    for (; s < n; s += 8) {
        float aC = 0.f;
        bf16x8 vC0 = {0, 0, 0, 0, 0, 0, 0, 0};
        bf16x8 vC1 = {0, 0, 0, 0, 0, 0, 0, 0};
        if (s + 16 < n) {
            int sr = bsrc[base + s + 16];
            aC = bf2f(balpha[(base + s + 16) * 8 + l8]);
            const unsigned short* vp = v + (size_t)sr * 128 + l8 * 16;
            vC0 = *reinterpret_cast<const bf16x8*>(vp);
            vC1 = *reinterpret_cast<const bf16x8*>(vp + 8);
        }
#pragma unroll
        for (int j = 0; j < 8; ++j)
            acc[j] += aA * bf2f((unsigned short)vA0[j]);
#pragma unroll
        for (int j = 0; j < 8; ++j)
            acc[8 + j] += aA * bf2f((unsigned short)vA1[j]);
        aA = aB; vA0 = vB0; vA1 = vB1;
        aB = aC; vB0 = vC0; vB1 = vC1;
    }

    // combine the eight ways
#pragma unroll
    for (int j = 0; j < 16; ++j) {
        acc[j] += __shfl_xor(acc[j], 8);
        acc[j] += __shfl_xor(acc[j], 16);
        acc[j] += __shfl_xor(acc[j], 32);
    }

    if (way == 0) {
        float* op = out + (size_t)node * 128 + l8 * 16;
        *reinterpret_cast<float4*>(op)      = make_float4(acc[0],  acc[1],  acc[2],  acc[3]);
        *reinterpret_cast<float4*>(op + 4)  = make_float4(acc[4],  acc[5],  acc[6],  acc[7]);
        *reinterpret_cast<float4*>(op + 8)  = make_float4(acc[8],  acc[9],  acc[10], acc[11]);
        *reinterpret_cast<float4*>(op + 12) = make_float4(acc[12], acc[13], acc[14], acc[15]);
    }
}

extern "C" void kernel_launch(void* const* d_in, const int* in_sizes, int n_in,
                              void* d_out, int out_size, void* d_ws, size_t ws_size,
                              hipStream_t stream) {
    const float* x    = (const float*)d_in[0];
    const float* w_ij = (const float*)d_in[1];
    const int* eidx   = (const int*)d_in[2];
    const float* cut  = (const float*)d_in[3];
    const float* Wq   = (const float*)d_in[4];
    const float* Wk   = (const float*)d_in[5];
    const float* Wv   = (const float*)d_in[6];
    float* out = (float*)d_out;

    const size_t nq = (size_t)N_NODES * HIDDEN;
    unsigned short* q = (unsigned short*)d_ws;
    unsigned short* k = q + nq;
    unsigned short* v = k + nq;
    int* cnt = (int*)(v + nq);
    int* bsrc = cnt + N_NODES;
    unsigned short* balpha = (unsigned short*)(bsrc + (size_t)N_NODES * BCAP);
    bf16x8* wb = (bf16x8*)(balpha + (size_t)N_NODES * BCAP * 8);

    // W -> bf16 fragment layout (once per launch, ~2 us).
    wprep_kernel<<<24, 256, 0, stream>>>(Wq, Wk, Wv, wb);

    // QKV projection (MFMA, bf16 out, M=128); also zeroes cnt[].
    dim3 ggrid((N_NODES + 127) / 128);
    qkv_mfma_kernel<<<ggrid, 512, 0, stream>>>(x, wb, q, k, v, cnt, N_NODES);

    // Fused edge pass: alpha + slot-ordered bucket store (8 lanes/edge).
    dim3 egrid((N_EDGES + 31) / 32);
    edge_kernel<<<egrid, 256, 0, stream>>>(q, k, w_ij, eidx, cut, cnt,
                                           bsrc, balpha, N_EDGES);

    // Node-parallel gather (one node per wave, 8-way x 8-lane).
    dim3 ngrid((N_NODES + 3) / 4);
    gather_kernel<<<ngrid, 256, 0, stream>>>(v, cnt, bsrc, balpha, out, N_NODES);
}